// Round 15
// baseline (208.960 us; speedup 1.0000x reference)
//
#include <hip/hip_runtime.h>
#include <hip/hip_fp16.h>
#include <math.h>

// ---------------- small utils ----------------
__global__ void zero32(int* __restrict__ p, int n) {
    int i = blockIdx.x * blockDim.x + threadIdx.x;
    if (i < n) p[i] = 0;
}

// ---------------- degree + per-edge rank (counting-sort split) ----------------
__global__ void hist_rank(const int* __restrict__ dst, int* __restrict__ cnt,
                          unsigned short* __restrict__ rank, int E) {
    int e = blockIdx.x * blockDim.x + threadIdx.x;
    if (e < E) rank[e] = (unsigned short)atomicAdd(&cnt[dst[e]], 1);
}

// ---- hierarchical scan (+ fused dinv computation) ----
__global__ __launch_bounds__(256) void scan1_dinv(const int* __restrict__ cnt,
                                                  int* __restrict__ excl,
                                                  int* __restrict__ sums,
                                                  float* __restrict__ dinv, int n) {
    int i = blockIdx.x * 256 + threadIdx.x;
    int v = (i < n) ? cnt[i] : 0;
    if (i < n) dinv[i] = rsqrtf((float)(v + 1));  // +1 self-loop
    int lane = threadIdx.x & 63;
    int w = threadIdx.x >> 6;
    int s = v;
#pragma unroll
    for (int off = 1; off < 64; off <<= 1) {
        int t = __shfl_up(s, off, 64);
        if (lane >= off) s += t;
    }
    __shared__ int wsum[4];
    if (lane == 63) wsum[w] = s;
    __syncthreads();
    int woff = 0;
#pragma unroll
    for (int k = 0; k < 3; ++k) if (k < w) woff += wsum[k];
    int incl = s + woff;
    if (i < n) excl[i] = incl - v;
    if (threadIdx.x == 255) sums[blockIdx.x] = incl;
}

__global__ __launch_bounds__(256) void scan2(int* __restrict__ sums, int nb) {
    int t = threadIdx.x;
    int v = (t < nb) ? sums[t] : 0;
    int lane = t & 63;
    int w = t >> 6;
    int s = v;
#pragma unroll
    for (int off = 1; off < 64; off <<= 1) {
        int u = __shfl_up(s, off, 64);
        if (lane >= off) s += u;
    }
    __shared__ int wsum[4];
    if (lane == 63) wsum[w] = s;
    __syncthreads();
    int woff = 0;
#pragma unroll
    for (int k = 0; k < 3; ++k) if (k < w) woff += wsum[k];
    int incl = s + woff;
    if (t < nb) sums[t] = incl - v;  // exclusive
}

__global__ __launch_bounds__(256) void scan3(const int* __restrict__ excl,
                                             const int* __restrict__ sums,
                                             int* __restrict__ rowptr, int n, int E) {
    int i = blockIdx.x * 256 + threadIdx.x;
    if (i < n) rowptr[i] = excl[i] + sums[i >> 8];
    if (i == n) rowptr[n] = E;
}

// atomic-free placement, XCD-partitioned for col write locality
__global__ void fill_place(const int* __restrict__ src, const int* __restrict__ dst,
                           const unsigned short* __restrict__ rank,
                           const int* __restrict__ rowptr,
                           unsigned short* __restrict__ col, int E, int n) {
    const int g    = blockIdx.x & 7;
    const int nblk = gridDim.x >> 3;
    const int bid  = blockIdx.x >> 3;
    const int lo = (int)(((long)g * n) >> 3);
    const int hi = (int)(((long)(g + 1) * n) >> 3);
    for (long e = (long)bid * blockDim.x + threadIdx.x; e < E;
         e += (long)nblk * blockDim.x) {
        int d = dst[e];
        if (d < lo || d >= hi) continue;
        col[rowptr[d] + rank[e]] = (unsigned short)src[e];
    }
}

#define RL(x, k) __int_as_float(__builtin_amdgcn_readlane(__float_as_int(x), (k)))

// ---------------- GEMM1: Y[n,64] = fp16( dinv[r] * (X[n,128] @ W[128,64]) ) ------
template <int K>
__global__ __launch_bounds__(256) void gemm_bcast_scaled(const float* __restrict__ X,
                                                         const float* __restrict__ W,
                                                         const float* __restrict__ dinv,
                                                         __half* __restrict__ Y, int n) {
    const int lane = threadIdx.x & 63;
    const long wid = (((long)blockIdx.x * blockDim.x) + threadIdx.x) >> 6;
    const long nw  = ((long)gridDim.x * blockDim.x) >> 6;

    float wr[K];
#pragma unroll
    for (int k = 0; k < K; ++k) wr[k] = W[k * 64 + lane];
#pragma unroll
    for (int k = 0; k < K; ++k) asm volatile("" : "+v"(wr[k]));

    long r0 = wid;
    if (r0 >= n) return;
    float xa0 = X[r0 * K + lane];
    float xb0 = 0.f;
    if constexpr (K > 64) xb0 = X[r0 * K + 64 + lane];
    float dv0 = dinv[r0];

    long r1 = r0 + nw;
    bool h1 = r1 < n;
    long rc1 = h1 ? r1 : r0;
    float xa1 = X[rc1 * K + lane];
    float xb1 = 0.f;
    if constexpr (K > 64) xb1 = X[rc1 * K + 64 + lane];
    float dv1 = dinv[rc1];

    while (true) {
        long r2 = r1 + nw;
        bool h2 = h1 && (r2 < n);
        long rc2 = h2 ? r2 : r0;
        float xa2 = X[rc2 * K + lane];
        float xb2 = 0.f;
        if constexpr (K > 64) xb2 = X[rc2 * K + 64 + lane];
        float dv2 = dinv[rc2];

        float a0 = 0.f, a1 = 0.f, a2 = 0.f, a3 = 0.f;
#pragma unroll
        for (int k = 0; k < 64; k += 4) {
            a0 = fmaf(RL(xa0, k + 0), wr[k + 0], a0);
            a1 = fmaf(RL(xa0, k + 1), wr[k + 1], a1);
            a2 = fmaf(RL(xa0, k + 2), wr[k + 2], a2);
            a3 = fmaf(RL(xa0, k + 3), wr[k + 3], a3);
        }
        if constexpr (K > 64) {
#pragma unroll
            for (int k = 0; k < 64; k += 4) {
                a0 = fmaf(RL(xb0, k + 0), wr[64 + k + 0], a0);
                a1 = fmaf(RL(xb0, k + 1), wr[64 + k + 1], a1);
                a2 = fmaf(RL(xb0, k + 2), wr[64 + k + 2], a2);
                a3 = fmaf(RL(xb0, k + 3), wr[64 + k + 3], a3);
            }
        }
        Y[r0 * 64 + lane] = __float2half(dv0 * ((a0 + a1) + (a2 + a3)));
        if (!h1) break;
        r0 = r1; xa0 = xa1; xb0 = xb1; dv0 = dv1;
        r1 = r2; h1 = h2; xa1 = xa2; xb1 = xb2; dv1 = dv2;
    }
}

// ---------------- two-node gather-sum over fp16 H', pipelined col stream --------
#define HG(idx) __half2float(Hp[(long)(idx) * 64 + j])
__device__ __forceinline__ void agg2(const __half* __restrict__ Hp,
                                     const int* __restrict__ rowptr,
                                     const unsigned short* __restrict__ col,
                                     long vA, long vB, int j, bool hasB,
                                     float& sumA, float& sumB) {
    float a0 = HG(vA), a1 = 0.f, a2 = 0.f, a3 = 0.f;
    float b0 = 0.f, b1 = 0.f, b2 = 0.f, b3 = 0.f;
    int pA = rowptr[vA], pA1 = rowptr[vA + 1];
    int pB = 0, pB1 = 0;
    if (hasB) { b0 = HG(vB); pB = rowptr[vB]; pB1 = rowptr[vB + 1]; }
    if ((pA & 1) && pA < pA1) { a1 += HG(col[pA]); ++pA; }
    if ((pB & 1) && pB < pB1) { b1 += HG(col[pB]); ++pB; }
    unsigned int cA01 = *(const unsigned int*)(col + pA);
    unsigned int cA23 = *(const unsigned int*)(col + pA + 2);
    unsigned int cB01 = *(const unsigned int*)(col + pB);
    unsigned int cB23 = *(const unsigned int*)(col + pB + 2);
    while (pA + 4 <= pA1 && pB + 4 <= pB1) {
        unsigned int nA01 = *(const unsigned int*)(col + pA + 4);
        unsigned int nA23 = *(const unsigned int*)(col + pA + 6);
        unsigned int nB01 = *(const unsigned int*)(col + pB + 4);
        unsigned int nB23 = *(const unsigned int*)(col + pB + 6);
        float hA0 = HG(cA01 & 0xFFFFu);
        float hA1 = HG(cA01 >> 16);
        float hA2 = HG(cA23 & 0xFFFFu);
        float hA3 = HG(cA23 >> 16);
        float hB0 = HG(cB01 & 0xFFFFu);
        float hB1 = HG(cB01 >> 16);
        float hB2 = HG(cB23 & 0xFFFFu);
        float hB3 = HG(cB23 >> 16);
        a0 += hA0; a1 += hA1; a2 += hA2; a3 += hA3;
        b0 += hB0; b1 += hB1; b2 += hB2; b3 += hB3;
        cA01 = nA01; cA23 = nA23; cB01 = nB01; cB23 = nB23;
        pA += 4; pB += 4;
    }
    for (; pA + 4 <= pA1; pA += 4) {
        float h0 = HG(cA01 & 0xFFFFu);
        float h1 = HG(cA01 >> 16);
        float h2 = HG(cA23 & 0xFFFFu);
        float h3 = HG(cA23 >> 16);
        a0 += h0; a1 += h1; a2 += h2; a3 += h3;
        cA01 = *(const unsigned int*)(col + pA + 4);
        cA23 = *(const unsigned int*)(col + pA + 6);
    }
    for (; pA < pA1; ++pA) a1 += HG(col[pA]);
    for (; pB + 4 <= pB1; pB += 4) {
        float h0 = HG(cB01 & 0xFFFFu);
        float h1 = HG(cB01 >> 16);
        float h2 = HG(cB23 & 0xFFFFu);
        float h3 = HG(cB23 >> 16);
        b0 += h0; b1 += h1; b2 += h2; b3 += h3;
        cB01 = *(const unsigned int*)(col + pB + 4);
        cB23 = *(const unsigned int*)(col + pB + 6);
    }
    for (; pB < pB1; ++pB) b1 += HG(col[pB]);
    sumA = (a0 + a1) + (a2 + a3);
    sumB = (b0 + b1) + (b2 + b3);
}

// ---------------- layer1-agg + layer2-GEMM fused, 2 nodes/wave ----------------
__global__ __launch_bounds__(256) void agg_gemm64(const __half* __restrict__ Hp,
                                                  const int* __restrict__ rowptr,
                                                  const unsigned short* __restrict__ col,
                                                  const float* __restrict__ dinv,
                                                  const float* __restrict__ bias,
                                                  const float* __restrict__ W2,
                                                  __half* __restrict__ out, int n) {
    const int j = threadIdx.x & 63;
    const long wid = (((long)blockIdx.x * blockDim.x) + threadIdx.x) >> 6;
    const long NW  = ((long)gridDim.x * blockDim.x) >> 6;
    float wr[64];
#pragma unroll
    for (int k = 0; k < 64; ++k) wr[k] = W2[k * 64 + j];
#pragma unroll
    for (int k = 0; k < 64; ++k) asm volatile("" : "+v"(wr[k]));
    const float bj = bias[j];
    for (long vA = wid; vA < n; vA += 2 * NW) {
        long vB = vA + NW;
        bool hasB = vB < n;
        float sA, sB;
        agg2(Hp, rowptr, col, vA, vB, j, hasB, sA, sB);
        float diA = dinv[vA];
        float diB = hasB ? dinv[vB] : 0.f;
        float gA = fmaxf(diA * sA + bj, 0.f);
        float gB = fmaxf(diB * sB + bj, 0.f);
        float a0 = 0.f, a1 = 0.f, a2 = 0.f, a3 = 0.f;
        float b0 = 0.f, b1 = 0.f, b2 = 0.f, b3 = 0.f;
#pragma unroll
        for (int k = 0; k < 64; k += 4) {
            float w0 = wr[k + 0], w1 = wr[k + 1], w2 = wr[k + 2], w3 = wr[k + 3];
            a0 = fmaf(RL(gA, k + 0), w0, a0);
            b0 = fmaf(RL(gB, k + 0), w0, b0);
            a1 = fmaf(RL(gA, k + 1), w1, a1);
            b1 = fmaf(RL(gB, k + 1), w1, b1);
            a2 = fmaf(RL(gA, k + 2), w2, a2);
            b2 = fmaf(RL(gB, k + 2), w2, b2);
            a3 = fmaf(RL(gA, k + 3), w3, a3);
            b3 = fmaf(RL(gB, k + 3), w3, b3);
        }
        out[vA * 64 + j] = __float2half(diA * ((a0 + a1) + (a2 + a3)));
        if (hasB) out[vB * 64 + j] = __float2half(diB * ((b0 + b1) + (b2 + b3)));
    }
}

// ---------------- layer2-agg + head-dot + pool, 2 nodes/wave ----------------
__global__ __launch_bounds__(256) void agg_pool(const __half* __restrict__ Hp,
                                                const int* __restrict__ rowptr,
                                                const unsigned short* __restrict__ col,
                                                const float* __restrict__ dinv,
                                                const float* __restrict__ bias,
                                                const float* __restrict__ Wl,
                                                const int* __restrict__ batch,
                                                float* __restrict__ part,
                                                float* __restrict__ partc, int n) {
    __shared__ float lp[256];
    __shared__ float lc[256];
    lp[threadIdx.x] = 0.f;
    lc[threadIdx.x] = 0.f;
    __syncthreads();
    const int j  = threadIdx.x & 63;
    const int wv = threadIdx.x >> 6;
    const float bj  = bias[j];
    const float wlj = Wl[j];
    const long wid = (long)blockIdx.x * 4 + wv;
    const long NW  = (long)gridDim.x * 4;
    for (long vA = wid; vA < n; vA += 2 * NW) {
        long vB = vA + NW;
        bool hasB = vB < n;
        float sA, sB;
        agg2(Hp, rowptr, col, vA, vB, j, hasB, sA, sB);
        float diA = dinv[vA];
        float diB = hasB ? dinv[vB] : 0.f;
        float valA = fmaxf(diA * sA + bj, 0.f) * wlj;
        float valB = fmaxf(diB * sB + bj, 0.f) * wlj;
#pragma unroll
        for (int off = 32; off > 0; off >>= 1) {
            valA += __shfl_down(valA, off, 64);
            valB += __shfl_down(valB, off, 64);
        }
        if (j == 0) {
            atomicAdd(&lp[batch[vA]], valA);
            atomicAdd(&lc[batch[vA]], 1.0f);
            if (hasB) {
                atomicAdd(&lp[batch[vB]], valB);
                atomicAdd(&lc[batch[vB]], 1.0f);
            }
        }
    }
    __syncthreads();
    long o = (long)blockIdx.x * 256 + threadIdx.x;
    part[o]  = lp[threadIdx.x];
    partc[o] = lc[threadIdx.x];
}

__global__ __launch_bounds__(256) void pool_final(const float* __restrict__ part,
                                                  const float* __restrict__ partc,
                                                  const float* __restrict__ bl,
                                                  float* __restrict__ out, int nblk) {
    int g = blockIdx.x;
    int t = threadIdx.x;
    float s = 0.f, c = 0.f;
    for (int b = t; b < nblk; b += 256) {
        s += part[(long)b * 256 + g];
        c += partc[(long)b * 256 + g];
    }
    __shared__ float sp[256];
    __shared__ float sc[256];
    sp[t] = s;
    sc[t] = c;
    __syncthreads();
    for (int off = 128; off > 0; off >>= 1) {
        if (t < off) { sp[t] += sp[t + off]; sc[t] += sc[t + off]; }
        __syncthreads();
    }
    if (t == 0) out[g] = sp[0] / fmaxf(sc[0], 1.0f) + bl[0];
}

extern "C" void kernel_launch(void* const* d_in, const int* in_sizes, int n_in,
                              void* d_out, int out_size, void* d_ws, size_t ws_size,
                              hipStream_t stream) {
    const float* x  = (const float*)d_in[0];
    const float* W1 = (const float*)d_in[1];
    const float* b1 = (const float*)d_in[2];
    const float* W2 = (const float*)d_in[3];
    const float* b2 = (const float*)d_in[4];
    const float* Wl = (const float*)d_in[5];
    const float* bl = (const float*)d_in[6];
    const int* edge_index = (const int*)d_in[7];
    const int* batch      = (const int*)d_in[8];

    const int n = in_sizes[0] / 128;   // 50000 (< 65536 for ushort cols)
    const int E = in_sizes[7] / 2;     // 800000
    const int G = out_size;            // 256
    const int* src = edge_index;
    const int* dst = edge_index + E;

    char* ws = (char*)d_ws;
    size_t off = 0;
    auto alloc = [&](size_t bytes) { void* p = ws + off; off = (off + bytes + 255) & ~(size_t)255; return p; };
    int*            cntv   = (int*)           alloc((size_t)n * 4);
    float*          dinv   = (float*)         alloc((size_t)n * 4);
    int*            rowptr = (int*)           alloc((size_t)(n + 1) * 4);
    int*            excl   = (int*)           alloc((size_t)n * 4);
    int*            sums   = (int*)           alloc((size_t)256 * 4);
    unsigned short* rank   = (unsigned short*)alloc((size_t)E * 2);
    unsigned short* col    = (unsigned short*)alloc((size_t)E * 2 + 64);  // +slop
    __half*         bufA   = (__half*)        alloc((size_t)n * 64 * 2);
    __half*         bufB   = (__half*)        alloc((size_t)n * 64 * 2);
    const int PBLK = 2048;
    float*          part   = (float*)         alloc((size_t)PBLK * 256 * 4);
    float*          partc  = (float*)         alloc((size_t)PBLK * 256 * 4);

    const int T = 256;
    const int nchunks = (n + 255) / 256;
    // ---- CSR build (shared by both layers) ----
    zero32<<<(n + T - 1) / T, T, 0, stream>>>(cntv, n);
    hist_rank<<<(E + T - 1) / T, T, 0, stream>>>(dst, cntv, rank, E);
    scan1_dinv<<<nchunks, T, 0, stream>>>(cntv, excl, sums, dinv, n);
    scan2<<<1, T, 0, stream>>>(sums, nchunks);
    scan3<<<(n + 1 + T - 1) / T, T, 0, stream>>>(excl, sums, rowptr, n, E);
    fill_place<<<1024, T, 0, stream>>>(src, dst, rank, rowptr, col, E, n);

    // ---- layer 1 GEMM (writes dinv-scaled h1' in fp16) ----
    gemm_bcast_scaled<128><<<768, T, 0, stream>>>(x, W1, dinv, bufA, n);
    // ---- layer1-agg + layer2-GEMM fused (writes dinv-scaled h2' in fp16) ----
    agg_gemm64<<<2048, T, 0, stream>>>(bufA, rowptr, col, dinv, b1, W2, bufB, n);
    // ---- layer2-agg + head + pooling partials ----
    agg_pool<<<PBLK, T, 0, stream>>>(bufB, rowptr, col, dinv, b2, Wl, batch, part, partc, n);
    pool_final<<<G, T, 0, stream>>>(part, partc, bl, (float*)d_out, PBLK);
}

// Round 16
// 208.950 us; speedup vs baseline: 1.0000x; 1.0000x over previous
//
#include <hip/hip_runtime.h>
#include <hip/hip_fp16.h>
#include <math.h>

// ---------------- small utils ----------------
__global__ void zero32(int* __restrict__ p, int n) {
    int i = blockIdx.x * blockDim.x + threadIdx.x;
    if (i < n) p[i] = 0;
}

// ---------------- degree + per-edge rank (counting-sort split) ----------------
__global__ void hist_rank(const int* __restrict__ dst, int* __restrict__ cnt,
                          unsigned short* __restrict__ rank, int E) {
    int e = blockIdx.x * blockDim.x + threadIdx.x;
    if (e < E) rank[e] = (unsigned short)atomicAdd(&cnt[dst[e]], 1);
}

// ---- hierarchical scan (+ fused dinv computation) ----
__global__ __launch_bounds__(256) void scan1_dinv(const int* __restrict__ cnt,
                                                  int* __restrict__ excl,
                                                  int* __restrict__ sums,
                                                  float* __restrict__ dinv, int n) {
    int i = blockIdx.x * 256 + threadIdx.x;
    int v = (i < n) ? cnt[i] : 0;
    if (i < n) dinv[i] = rsqrtf((float)(v + 1));  // +1 self-loop
    int lane = threadIdx.x & 63;
    int w = threadIdx.x >> 6;
    int s = v;
#pragma unroll
    for (int off = 1; off < 64; off <<= 1) {
        int t = __shfl_up(s, off, 64);
        if (lane >= off) s += t;
    }
    __shared__ int wsum[4];
    if (lane == 63) wsum[w] = s;
    __syncthreads();
    int woff = 0;
#pragma unroll
    for (int k = 0; k < 3; ++k) if (k < w) woff += wsum[k];
    int incl = s + woff;
    if (i < n) excl[i] = incl - v;
    if (threadIdx.x == 255) sums[blockIdx.x] = incl;
}

__global__ __launch_bounds__(256) void scan2(int* __restrict__ sums, int nb) {
    int t = threadIdx.x;
    int v = (t < nb) ? sums[t] : 0;
    int lane = t & 63;
    int w = t >> 6;
    int s = v;
#pragma unroll
    for (int off = 1; off < 64; off <<= 1) {
        int u = __shfl_up(s, off, 64);
        if (lane >= off) s += u;
    }
    __shared__ int wsum[4];
    if (lane == 63) wsum[w] = s;
    __syncthreads();
    int woff = 0;
#pragma unroll
    for (int k = 0; k < 3; ++k) if (k < w) woff += wsum[k];
    int incl = s + woff;
    if (t < nb) sums[t] = incl - v;  // exclusive
}

__global__ __launch_bounds__(256) void scan3(const int* __restrict__ excl,
                                             const int* __restrict__ sums,
                                             int* __restrict__ rowptr, int n, int E) {
    int i = blockIdx.x * 256 + threadIdx.x;
    if (i < n) rowptr[i] = excl[i] + sums[i >> 8];
    if (i == n) rowptr[n] = E;
}

// atomic-free placement, XCD-partitioned for col write locality
__global__ void fill_place(const int* __restrict__ src, const int* __restrict__ dst,
                           const unsigned short* __restrict__ rank,
                           const int* __restrict__ rowptr,
                           unsigned short* __restrict__ col, int E, int n) {
    const int g    = blockIdx.x & 7;
    const int nblk = gridDim.x >> 3;
    const int bid  = blockIdx.x >> 3;
    const int lo = (int)(((long)g * n) >> 3);
    const int hi = (int)(((long)(g + 1) * n) >> 3);
    for (long e = (long)bid * blockDim.x + threadIdx.x; e < E;
         e += (long)nblk * blockDim.x) {
        int d = dst[e];
        if (d < lo || d >= hi) continue;
        col[rowptr[d] + rank[e]] = (unsigned short)src[e];
    }
}

#define RL(x, k) __int_as_float(__builtin_amdgcn_readlane(__float_as_int(x), (k)))

// ---------------- GEMM1: Y[n,64] = fp16( dinv[r] * (X[n,128] @ W[128,64]) ) ------
template <int K>
__global__ __launch_bounds__(256) void gemm_bcast_scaled(const float* __restrict__ X,
                                                         const float* __restrict__ W,
                                                         const float* __restrict__ dinv,
                                                         __half* __restrict__ Y, int n) {
    const int lane = threadIdx.x & 63;
    const long wid = (((long)blockIdx.x * blockDim.x) + threadIdx.x) >> 6;
    const long nw  = ((long)gridDim.x * blockDim.x) >> 6;

    float wr[K];
#pragma unroll
    for (int k = 0; k < K; ++k) wr[k] = W[k * 64 + lane];
#pragma unroll
    for (int k = 0; k < K; ++k) asm volatile("" : "+v"(wr[k]));

    long r0 = wid;
    if (r0 >= n) return;
    float xa0 = X[r0 * K + lane];
    float xb0 = 0.f;
    if constexpr (K > 64) xb0 = X[r0 * K + 64 + lane];
    float dv0 = dinv[r0];

    long r1 = r0 + nw;
    bool h1 = r1 < n;
    long rc1 = h1 ? r1 : r0;
    float xa1 = X[rc1 * K + lane];
    float xb1 = 0.f;
    if constexpr (K > 64) xb1 = X[rc1 * K + 64 + lane];
    float dv1 = dinv[rc1];

    while (true) {
        long r2 = r1 + nw;
        bool h2 = h1 && (r2 < n);
        long rc2 = h2 ? r2 : r0;
        float xa2 = X[rc2 * K + lane];
        float xb2 = 0.f;
        if constexpr (K > 64) xb2 = X[rc2 * K + 64 + lane];
        float dv2 = dinv[rc2];

        float a0 = 0.f, a1 = 0.f, a2 = 0.f, a3 = 0.f;
#pragma unroll
        for (int k = 0; k < 64; k += 4) {
            a0 = fmaf(RL(xa0, k + 0), wr[k + 0], a0);
            a1 = fmaf(RL(xa0, k + 1), wr[k + 1], a1);
            a2 = fmaf(RL(xa0, k + 2), wr[k + 2], a2);
            a3 = fmaf(RL(xa0, k + 3), wr[k + 3], a3);
        }
        if constexpr (K > 64) {
#pragma unroll
            for (int k = 0; k < 64; k += 4) {
                a0 = fmaf(RL(xb0, k + 0), wr[64 + k + 0], a0);
                a1 = fmaf(RL(xb0, k + 1), wr[64 + k + 1], a1);
                a2 = fmaf(RL(xb0, k + 2), wr[64 + k + 2], a2);
                a3 = fmaf(RL(xb0, k + 3), wr[64 + k + 3], a3);
            }
        }
        Y[r0 * 64 + lane] = __float2half(dv0 * ((a0 + a1) + (a2 + a3)));
        if (!h1) break;
        r0 = r1; xa0 = xa1; xb0 = xb1; dv0 = dv1;
        r1 = r2; h1 = h2; xa1 = xa2; xb1 = xb2; dv1 = dv2;
    }
}

// ---------------- two-node gather-sum over fp16 H', pipelined col stream --------
#define HG(idx) __half2float(Hp[(long)(idx) * 64 + j])
__device__ __forceinline__ void agg2(const __half* __restrict__ Hp,
                                     const int* __restrict__ rowptr,
                                     const unsigned short* __restrict__ col,
                                     long vA, long vB, int j, bool hasB,
                                     float& sumA, float& sumB) {
    float a0 = HG(vA), a1 = 0.f, a2 = 0.f, a3 = 0.f;
    float b0 = 0.f, b1 = 0.f, b2 = 0.f, b3 = 0.f;
    int pA = rowptr[vA], pA1 = rowptr[vA + 1];
    int pB = 0, pB1 = 0;
    if (hasB) { b0 = HG(vB); pB = rowptr[vB]; pB1 = rowptr[vB + 1]; }
    if ((pA & 1) && pA < pA1) { a1 += HG(col[pA]); ++pA; }
    if ((pB & 1) && pB < pB1) { b1 += HG(col[pB]); ++pB; }
    unsigned int cA01 = *(const unsigned int*)(col + pA);
    unsigned int cA23 = *(const unsigned int*)(col + pA + 2);
    unsigned int cB01 = *(const unsigned int*)(col + pB);
    unsigned int cB23 = *(const unsigned int*)(col + pB + 2);
    while (pA + 4 <= pA1 && pB + 4 <= pB1) {
        unsigned int nA01 = *(const unsigned int*)(col + pA + 4);
        unsigned int nA23 = *(const unsigned int*)(col + pA + 6);
        unsigned int nB01 = *(const unsigned int*)(col + pB + 4);
        unsigned int nB23 = *(const unsigned int*)(col + pB + 6);
        float hA0 = HG(cA01 & 0xFFFFu);
        float hA1 = HG(cA01 >> 16);
        float hA2 = HG(cA23 & 0xFFFFu);
        float hA3 = HG(cA23 >> 16);
        float hB0 = HG(cB01 & 0xFFFFu);
        float hB1 = HG(cB01 >> 16);
        float hB2 = HG(cB23 & 0xFFFFu);
        float hB3 = HG(cB23 >> 16);
        a0 += hA0; a1 += hA1; a2 += hA2; a3 += hA3;
        b0 += hB0; b1 += hB1; b2 += hB2; b3 += hB3;
        cA01 = nA01; cA23 = nA23; cB01 = nB01; cB23 = nB23;
        pA += 4; pB += 4;
    }
    for (; pA + 4 <= pA1; pA += 4) {
        float h0 = HG(cA01 & 0xFFFFu);
        float h1 = HG(cA01 >> 16);
        float h2 = HG(cA23 & 0xFFFFu);
        float h3 = HG(cA23 >> 16);
        a0 += h0; a1 += h1; a2 += h2; a3 += h3;
        cA01 = *(const unsigned int*)(col + pA + 4);
        cA23 = *(const unsigned int*)(col + pA + 6);
    }
    for (; pA < pA1; ++pA) a1 += HG(col[pA]);
    for (; pB + 4 <= pB1; pB += 4) {
        float h0 = HG(cB01 & 0xFFFFu);
        float h1 = HG(cB01 >> 16);
        float h2 = HG(cB23 & 0xFFFFu);
        float h3 = HG(cB23 >> 16);
        b0 += h0; b1 += h1; b2 += h2; b3 += h3;
        cB01 = *(const unsigned int*)(col + pB + 4);
        cB23 = *(const unsigned int*)(col + pB + 6);
    }
    for (; pB < pB1; ++pB) b1 += HG(col[pB]);
    sumA = (a0 + a1) + (a2 + a3);
    sumB = (b0 + b1) + (b2 + b3);
}

// ---------------- layer1-agg + layer2-GEMM fused, 2 nodes/wave ----------------
// NOTE: no register pin on wr[] here — pinning held 64 VGPRs and dropped
// occupancy 8->5 waves/SIMD (round 15: 52->81us). W2 is L1-resident; letting
// the compiler reload it overlaps the gather phase and keeps 8 waves/SIMD.
__global__ __launch_bounds__(256) void agg_gemm64(const __half* __restrict__ Hp,
                                                  const int* __restrict__ rowptr,
                                                  const unsigned short* __restrict__ col,
                                                  const float* __restrict__ dinv,
                                                  const float* __restrict__ bias,
                                                  const float* __restrict__ W2,
                                                  __half* __restrict__ out, int n) {
    const int j = threadIdx.x & 63;
    const long wid = (((long)blockIdx.x * blockDim.x) + threadIdx.x) >> 6;
    const long NW  = ((long)gridDim.x * blockDim.x) >> 6;
    const float bj = bias[j];
    for (long vA = wid; vA < n; vA += 2 * NW) {
        long vB = vA + NW;
        bool hasB = vB < n;
        float sA, sB;
        agg2(Hp, rowptr, col, vA, vB, j, hasB, sA, sB);
        float diA = dinv[vA];
        float diB = hasB ? dinv[vB] : 0.f;
        float gA = fmaxf(diA * sA + bj, 0.f);
        float gB = fmaxf(diB * sB + bj, 0.f);
        float a0 = 0.f, a1 = 0.f, a2 = 0.f, a3 = 0.f;
        float b0 = 0.f, b1 = 0.f, b2 = 0.f, b3 = 0.f;
#pragma unroll
        for (int k = 0; k < 64; k += 4) {
            float w0 = W2[(k + 0) * 64 + j];
            float w1 = W2[(k + 1) * 64 + j];
            float w2 = W2[(k + 2) * 64 + j];
            float w3 = W2[(k + 3) * 64 + j];
            a0 = fmaf(RL(gA, k + 0), w0, a0);
            b0 = fmaf(RL(gB, k + 0), w0, b0);
            a1 = fmaf(RL(gA, k + 1), w1, a1);
            b1 = fmaf(RL(gB, k + 1), w1, b1);
            a2 = fmaf(RL(gA, k + 2), w2, a2);
            b2 = fmaf(RL(gB, k + 2), w2, b2);
            a3 = fmaf(RL(gA, k + 3), w3, a3);
            b3 = fmaf(RL(gB, k + 3), w3, b3);
        }
        out[vA * 64 + j] = __float2half(diA * ((a0 + a1) + (a2 + a3)));
        if (hasB) out[vB * 64 + j] = __float2half(diB * ((b0 + b1) + (b2 + b3)));
    }
}

// ---------------- layer2-agg + head-dot + pool, 2 nodes/wave ----------------
__global__ __launch_bounds__(256) void agg_pool(const __half* __restrict__ Hp,
                                                const int* __restrict__ rowptr,
                                                const unsigned short* __restrict__ col,
                                                const float* __restrict__ dinv,
                                                const float* __restrict__ bias,
                                                const float* __restrict__ Wl,
                                                const int* __restrict__ batch,
                                                float* __restrict__ part,
                                                float* __restrict__ partc, int n) {
    __shared__ float lp[256];
    __shared__ float lc[256];
    lp[threadIdx.x] = 0.f;
    lc[threadIdx.x] = 0.f;
    __syncthreads();
    const int j  = threadIdx.x & 63;
    const int wv = threadIdx.x >> 6;
    const float bj  = bias[j];
    const float wlj = Wl[j];
    const long wid = (long)blockIdx.x * 4 + wv;
    const long NW  = (long)gridDim.x * 4;
    for (long vA = wid; vA < n; vA += 2 * NW) {
        long vB = vA + NW;
        bool hasB = vB < n;
        float sA, sB;
        agg2(Hp, rowptr, col, vA, vB, j, hasB, sA, sB);
        float diA = dinv[vA];
        float diB = hasB ? dinv[vB] : 0.f;
        float valA = fmaxf(diA * sA + bj, 0.f) * wlj;
        float valB = fmaxf(diB * sB + bj, 0.f) * wlj;
#pragma unroll
        for (int off = 32; off > 0; off >>= 1) {
            valA += __shfl_down(valA, off, 64);
            valB += __shfl_down(valB, off, 64);
        }
        if (j == 0) {
            atomicAdd(&lp[batch[vA]], valA);
            atomicAdd(&lc[batch[vA]], 1.0f);
            if (hasB) {
                atomicAdd(&lp[batch[vB]], valB);
                atomicAdd(&lc[batch[vB]], 1.0f);
            }
        }
    }
    __syncthreads();
    long o = (long)blockIdx.x * 256 + threadIdx.x;
    part[o]  = lp[threadIdx.x];
    partc[o] = lc[threadIdx.x];
}

__global__ __launch_bounds__(256) void pool_final(const float* __restrict__ part,
                                                  const float* __restrict__ partc,
                                                  const float* __restrict__ bl,
                                                  float* __restrict__ out, int nblk) {
    int g = blockIdx.x;
    int t = threadIdx.x;
    float s = 0.f, c = 0.f;
    for (int b = t; b < nblk; b += 256) {
        s += part[(long)b * 256 + g];
        c += partc[(long)b * 256 + g];
    }
    __shared__ float sp[256];
    __shared__ float sc[256];
    sp[t] = s;
    sc[t] = c;
    __syncthreads();
    for (int off = 128; off > 0; off >>= 1) {
        if (t < off) { sp[t] += sp[t + off]; sc[t] += sc[t + off]; }
        __syncthreads();
    }
    if (t == 0) out[g] = sp[0] / fmaxf(sc[0], 1.0f) + bl[0];
}

extern "C" void kernel_launch(void* const* d_in, const int* in_sizes, int n_in,
                              void* d_out, int out_size, void* d_ws, size_t ws_size,
                              hipStream_t stream) {
    const float* x  = (const float*)d_in[0];
    const float* W1 = (const float*)d_in[1];
    const float* b1 = (const float*)d_in[2];
    const float* W2 = (const float*)d_in[3];
    const float* b2 = (const float*)d_in[4];
    const float* Wl = (const float*)d_in[5];
    const float* bl = (const float*)d_in[6];
    const int* edge_index = (const int*)d_in[7];
    const int* batch      = (const int*)d_in[8];

    const int n = in_sizes[0] / 128;   // 50000 (< 65536 for ushort cols)
    const int E = in_sizes[7] / 2;     // 800000
    const int G = out_size;            // 256
    const int* src = edge_index;
    const int* dst = edge_index + E;

    char* ws = (char*)d_ws;
    size_t off = 0;
    auto alloc = [&](size_t bytes) { void* p = ws + off; off = (off + bytes + 255) & ~(size_t)255; return p; };
    int*            cntv   = (int*)           alloc((size_t)n * 4);
    float*          dinv   = (float*)         alloc((size_t)n * 4);
    int*            rowptr = (int*)           alloc((size_t)(n + 1) * 4);
    int*            excl   = (int*)           alloc((size_t)n * 4);
    int*            sums   = (int*)           alloc((size_t)256 * 4);
    unsigned short* rank   = (unsigned short*)alloc((size_t)E * 2);
    unsigned short* col    = (unsigned short*)alloc((size_t)E * 2 + 64);  // +slop
    __half*         bufA   = (__half*)        alloc((size_t)n * 64 * 2);
    __half*         bufB   = (__half*)        alloc((size_t)n * 64 * 2);
    const int PBLK = 2048;
    float*          part   = (float*)         alloc((size_t)PBLK * 256 * 4);
    float*          partc  = (float*)         alloc((size_t)PBLK * 256 * 4);

    const int T = 256;
    const int nchunks = (n + 255) / 256;
    // ---- CSR build (shared by both layers) ----
    zero32<<<(n + T - 1) / T, T, 0, stream>>>(cntv, n);
    hist_rank<<<(E + T - 1) / T, T, 0, stream>>>(dst, cntv, rank, E);
    scan1_dinv<<<nchunks, T, 0, stream>>>(cntv, excl, sums, dinv, n);
    scan2<<<1, T, 0, stream>>>(sums, nchunks);
    scan3<<<(n + 1 + T - 1) / T, T, 0, stream>>>(excl, sums, rowptr, n, E);
    fill_place<<<1024, T, 0, stream>>>(src, dst, rank, rowptr, col, E, n);

    // ---- layer 1 GEMM (writes dinv-scaled h1' in fp16) ----
    gemm_bcast_scaled<128><<<768, T, 0, stream>>>(x, W1, dinv, bufA, n);
    // ---- layer1-agg + layer2-GEMM fused (writes dinv-scaled h2' in fp16) ----
    agg_gemm64<<<2048, T, 0, stream>>>(bufA, rowptr, col, dinv, b1, W2, bufB, n);
    // ---- layer2-agg + head + pooling partials ----
    agg_pool<<<PBLK, T, 0, stream>>>(bufB, rowptr, col, dinv, b2, Wl, batch, part, partc, n);
    pool_final<<<G, T, 0, stream>>>(part, partc, bl, (float*)d_out, PBLK);
}

// Round 17
// 171.812 us; speedup vs baseline: 1.2162x; 1.2162x over previous
//
#include <hip/hip_runtime.h>
#include <hip/hip_fp16.h>
#include <math.h>

// ---------------- small utils ----------------
__global__ void zero32(int* __restrict__ p, int n) {
    int i = blockIdx.x * blockDim.x + threadIdx.x;
    if (i < n) p[i] = 0;
}

// ---------------- degree + per-edge rank (counting-sort split) ----------------
__global__ void hist_rank(const int* __restrict__ dst, int* __restrict__ cnt,
                          unsigned short* __restrict__ rank, int E) {
    int e = blockIdx.x * blockDim.x + threadIdx.x;
    if (e < E) rank[e] = (unsigned short)atomicAdd(&cnt[dst[e]], 1);
}

// ---- hierarchical scan (+ fused dinv computation) ----
__global__ __launch_bounds__(256) void scan1_dinv(const int* __restrict__ cnt,
                                                  int* __restrict__ excl,
                                                  int* __restrict__ sums,
                                                  float* __restrict__ dinv, int n) {
    int i = blockIdx.x * 256 + threadIdx.x;
    int v = (i < n) ? cnt[i] : 0;
    if (i < n) dinv[i] = rsqrtf((float)(v + 1));  // +1 self-loop
    int lane = threadIdx.x & 63;
    int w = threadIdx.x >> 6;
    int s = v;
#pragma unroll
    for (int off = 1; off < 64; off <<= 1) {
        int t = __shfl_up(s, off, 64);
        if (lane >= off) s += t;
    }
    __shared__ int wsum[4];
    if (lane == 63) wsum[w] = s;
    __syncthreads();
    int woff = 0;
#pragma unroll
    for (int k = 0; k < 3; ++k) if (k < w) woff += wsum[k];
    int incl = s + woff;
    if (i < n) excl[i] = incl - v;
    if (threadIdx.x == 255) sums[blockIdx.x] = incl;
}

__global__ __launch_bounds__(256) void scan2(int* __restrict__ sums, int nb) {
    int t = threadIdx.x;
    int v = (t < nb) ? sums[t] : 0;
    int lane = t & 63;
    int w = t >> 6;
    int s = v;
#pragma unroll
    for (int off = 1; off < 64; off <<= 1) {
        int u = __shfl_up(s, off, 64);
        if (lane >= off) s += u;
    }
    __shared__ int wsum[4];
    if (lane == 63) wsum[w] = s;
    __syncthreads();
    int woff = 0;
#pragma unroll
    for (int k = 0; k < 3; ++k) if (k < w) woff += wsum[k];
    int incl = s + woff;
    if (t < nb) sums[t] = incl - v;  // exclusive
}

__global__ __launch_bounds__(256) void scan3(const int* __restrict__ excl,
                                             const int* __restrict__ sums,
                                             int* __restrict__ rowptr, int n, int E) {
    int i = blockIdx.x * 256 + threadIdx.x;
    if (i < n) rowptr[i] = excl[i] + sums[i >> 8];
    if (i == n) rowptr[n] = E;
}

// atomic-free placement, XCD-partitioned for col write locality
__global__ void fill_place(const int* __restrict__ src, const int* __restrict__ dst,
                           const unsigned short* __restrict__ rank,
                           const int* __restrict__ rowptr,
                           unsigned short* __restrict__ col, int E, int n) {
    const int g    = blockIdx.x & 7;
    const int nblk = gridDim.x >> 3;
    const int bid  = blockIdx.x >> 3;
    const int lo = (int)(((long)g * n) >> 3);
    const int hi = (int)(((long)(g + 1) * n) >> 3);
    for (long e = (long)bid * blockDim.x + threadIdx.x; e < E;
         e += (long)nblk * blockDim.x) {
        int d = dst[e];
        if (d < lo || d >= hi) continue;
        col[rowptr[d] + rank[e]] = (unsigned short)src[e];
    }
}

#define RL(x, k) __int_as_float(__builtin_amdgcn_readlane(__float_as_int(x), (k)))

__device__ __forceinline__ float ldf(const float* p, long i) { return p[i]; }
__device__ __forceinline__ float ldf(const __half* p, long i) { return __half2float(p[i]); }

// ---------------- GEMM: Y[n,64] = fp16( dinv[r] * (X[n,K] @ W[K,64]) ) ----------
// Register-W readlane GEMM, depth-2 row prefetch. FMA-throughput kernel: W pin
// is intentional here (separate from the gather kernel so VGPR pressure is OK).
template <int K, typename XT>
__global__ __launch_bounds__(256) void gemm_bcast_scaled(const XT* __restrict__ X,
                                                         const float* __restrict__ W,
                                                         const float* __restrict__ dinv,
                                                         __half* __restrict__ Y, int n) {
    const int lane = threadIdx.x & 63;
    const long wid = (((long)blockIdx.x * blockDim.x) + threadIdx.x) >> 6;
    const long nw  = ((long)gridDim.x * blockDim.x) >> 6;

    float wr[K];
#pragma unroll
    for (int k = 0; k < K; ++k) wr[k] = W[k * 64 + lane];
#pragma unroll
    for (int k = 0; k < K; ++k) asm volatile("" : "+v"(wr[k]));

    long r0 = wid;
    if (r0 >= n) return;
    float xa0 = ldf(X, r0 * K + lane);
    float xb0 = 0.f;
    if constexpr (K > 64) xb0 = ldf(X, r0 * K + 64 + lane);
    float dv0 = dinv[r0];

    long r1 = r0 + nw;
    bool h1 = r1 < n;
    long rc1 = h1 ? r1 : r0;
    float xa1 = ldf(X, rc1 * K + lane);
    float xb1 = 0.f;
    if constexpr (K > 64) xb1 = ldf(X, rc1 * K + 64 + lane);
    float dv1 = dinv[rc1];

    while (true) {
        long r2 = r1 + nw;
        bool h2 = h1 && (r2 < n);
        long rc2 = h2 ? r2 : r0;
        float xa2 = ldf(X, rc2 * K + lane);
        float xb2 = 0.f;
        if constexpr (K > 64) xb2 = ldf(X, rc2 * K + 64 + lane);
        float dv2 = dinv[rc2];

        float a0 = 0.f, a1 = 0.f, a2 = 0.f, a3 = 0.f;
#pragma unroll
        for (int k = 0; k < 64; k += 4) {
            a0 = fmaf(RL(xa0, k + 0), wr[k + 0], a0);
            a1 = fmaf(RL(xa0, k + 1), wr[k + 1], a1);
            a2 = fmaf(RL(xa0, k + 2), wr[k + 2], a2);
            a3 = fmaf(RL(xa0, k + 3), wr[k + 3], a3);
        }
        if constexpr (K > 64) {
#pragma unroll
            for (int k = 0; k < 64; k += 4) {
                a0 = fmaf(RL(xb0, k + 0), wr[64 + k + 0], a0);
                a1 = fmaf(RL(xb0, k + 1), wr[64 + k + 1], a1);
                a2 = fmaf(RL(xb0, k + 2), wr[64 + k + 2], a2);
                a3 = fmaf(RL(xb0, k + 3), wr[64 + k + 3], a3);
            }
        }
        Y[r0 * 64 + lane] = __float2half(dv0 * ((a0 + a1) + (a2 + a3)));
        if (!h1) break;
        r0 = r1; xa0 = xa1; xb0 = xb1; dv0 = dv1;
        r1 = r2; h1 = h2; xa1 = xa2; xb1 = xb2; dv1 = dv2;
    }
}

// ---------------- two-node gather-sum over fp16 H', pipelined col stream --------
#define HG(idx) __half2float(Hp[(long)(idx) * 64 + j])
__device__ __forceinline__ void agg2(const __half* __restrict__ Hp,
                                     const int* __restrict__ rowptr,
                                     const unsigned short* __restrict__ col,
                                     long vA, long vB, int j, bool hasB,
                                     float& sumA, float& sumB) {
    float a0 = HG(vA), a1 = 0.f, a2 = 0.f, a3 = 0.f;
    float b0 = 0.f, b1 = 0.f, b2 = 0.f, b3 = 0.f;
    int pA = rowptr[vA], pA1 = rowptr[vA + 1];
    int pB = 0, pB1 = 0;
    if (hasB) { b0 = HG(vB); pB = rowptr[vB]; pB1 = rowptr[vB + 1]; }
    if ((pA & 1) && pA < pA1) { a1 += HG(col[pA]); ++pA; }
    if ((pB & 1) && pB < pB1) { b1 += HG(col[pB]); ++pB; }
    unsigned int cA01 = *(const unsigned int*)(col + pA);
    unsigned int cA23 = *(const unsigned int*)(col + pA + 2);
    unsigned int cB01 = *(const unsigned int*)(col + pB);
    unsigned int cB23 = *(const unsigned int*)(col + pB + 2);
    while (pA + 4 <= pA1 && pB + 4 <= pB1) {
        unsigned int nA01 = *(const unsigned int*)(col + pA + 4);
        unsigned int nA23 = *(const unsigned int*)(col + pA + 6);
        unsigned int nB01 = *(const unsigned int*)(col + pB + 4);
        unsigned int nB23 = *(const unsigned int*)(col + pB + 6);
        float hA0 = HG(cA01 & 0xFFFFu);
        float hA1 = HG(cA01 >> 16);
        float hA2 = HG(cA23 & 0xFFFFu);
        float hA3 = HG(cA23 >> 16);
        float hB0 = HG(cB01 & 0xFFFFu);
        float hB1 = HG(cB01 >> 16);
        float hB2 = HG(cB23 & 0xFFFFu);
        float hB3 = HG(cB23 >> 16);
        a0 += hA0; a1 += hA1; a2 += hA2; a3 += hA3;
        b0 += hB0; b1 += hB1; b2 += hB2; b3 += hB3;
        cA01 = nA01; cA23 = nA23; cB01 = nB01; cB23 = nB23;
        pA += 4; pB += 4;
    }
    for (; pA + 4 <= pA1; pA += 4) {
        float h0 = HG(cA01 & 0xFFFFu);
        float h1 = HG(cA01 >> 16);
        float h2 = HG(cA23 & 0xFFFFu);
        float h3 = HG(cA23 >> 16);
        a0 += h0; a1 += h1; a2 += h2; a3 += h3;
        cA01 = *(const unsigned int*)(col + pA + 4);
        cA23 = *(const unsigned int*)(col + pA + 6);
    }
    for (; pA < pA1; ++pA) a1 += HG(col[pA]);
    for (; pB + 4 <= pB1; pB += 4) {
        float h0 = HG(cB01 & 0xFFFFu);
        float h1 = HG(cB01 >> 16);
        float h2 = HG(cB23 & 0xFFFFu);
        float h3 = HG(cB23 >> 16);
        b0 += h0; b1 += h1; b2 += h2; b3 += h3;
        cB01 = *(const unsigned int*)(col + pB + 4);
        cB23 = *(const unsigned int*)(col + pB + 6);
    }
    for (; pB < pB1; ++pB) b1 += HG(col[pB]);
    sumA = (a0 + a1) + (a2 + a3);
    sumB = (b0 + b1) + (b2 + b3);
}

// ---------------- layer1 agg + relu -> g1 (fp16), 2 nodes/wave ----------------
// Pure gather kernel: low VGPR -> 8 waves/SIMD for latency hiding. The layer-2
// GEMM is a separate kernel (fusing it forced 64 W2 regs and 18% occupancy).
__global__ __launch_bounds__(256) void agg_relu16(const __half* __restrict__ Hp,
                                                  const int* __restrict__ rowptr,
                                                  const unsigned short* __restrict__ col,
                                                  const float* __restrict__ dinv,
                                                  const float* __restrict__ bias,
                                                  __half* __restrict__ out, int n) {
    const int j = threadIdx.x & 63;
    const long wid = (((long)blockIdx.x * blockDim.x) + threadIdx.x) >> 6;
    const long NW  = ((long)gridDim.x * blockDim.x) >> 6;
    const float bj = bias[j];
    for (long vA = wid; vA < n; vA += 2 * NW) {
        long vB = vA + NW;
        bool hasB = vB < n;
        float sA, sB;
        agg2(Hp, rowptr, col, vA, vB, j, hasB, sA, sB);
        float diA = dinv[vA];
        float diB = hasB ? dinv[vB] : 0.f;
        out[vA * 64 + j] = __float2half(fmaxf(diA * sA + bj, 0.f));
        if (hasB) out[vB * 64 + j] = __float2half(fmaxf(diB * sB + bj, 0.f));
    }
}

// ---------------- layer2-agg + head-dot + pool, 2 nodes/wave ----------------
__global__ __launch_bounds__(256) void agg_pool(const __half* __restrict__ Hp,
                                                const int* __restrict__ rowptr,
                                                const unsigned short* __restrict__ col,
                                                const float* __restrict__ dinv,
                                                const float* __restrict__ bias,
                                                const float* __restrict__ Wl,
                                                const int* __restrict__ batch,
                                                float* __restrict__ part,
                                                float* __restrict__ partc, int n) {
    __shared__ float lp[256];
    __shared__ float lc[256];
    lp[threadIdx.x] = 0.f;
    lc[threadIdx.x] = 0.f;
    __syncthreads();
    const int j  = threadIdx.x & 63;
    const int wv = threadIdx.x >> 6;
    const float bj  = bias[j];
    const float wlj = Wl[j];
    const long wid = (long)blockIdx.x * 4 + wv;
    const long NW  = (long)gridDim.x * 4;
    for (long vA = wid; vA < n; vA += 2 * NW) {
        long vB = vA + NW;
        bool hasB = vB < n;
        float sA, sB;
        agg2(Hp, rowptr, col, vA, vB, j, hasB, sA, sB);
        float diA = dinv[vA];
        float diB = hasB ? dinv[vB] : 0.f;
        float valA = fmaxf(diA * sA + bj, 0.f) * wlj;
        float valB = fmaxf(diB * sB + bj, 0.f) * wlj;
#pragma unroll
        for (int off = 32; off > 0; off >>= 1) {
            valA += __shfl_down(valA, off, 64);
            valB += __shfl_down(valB, off, 64);
        }
        if (j == 0) {
            atomicAdd(&lp[batch[vA]], valA);
            atomicAdd(&lc[batch[vA]], 1.0f);
            if (hasB) {
                atomicAdd(&lp[batch[vB]], valB);
                atomicAdd(&lc[batch[vB]], 1.0f);
            }
        }
    }
    __syncthreads();
    long o = (long)blockIdx.x * 256 + threadIdx.x;
    part[o]  = lp[threadIdx.x];
    partc[o] = lc[threadIdx.x];
}

__global__ __launch_bounds__(256) void pool_final(const float* __restrict__ part,
                                                  const float* __restrict__ partc,
                                                  const float* __restrict__ bl,
                                                  float* __restrict__ out, int nblk) {
    int g = blockIdx.x;
    int t = threadIdx.x;
    float s = 0.f, c = 0.f;
    for (int b = t; b < nblk; b += 256) {
        s += part[(long)b * 256 + g];
        c += partc[(long)b * 256 + g];
    }
    __shared__ float sp[256];
    __shared__ float sc[256];
    sp[t] = s;
    sc[t] = c;
    __syncthreads();
    for (int off = 128; off > 0; off >>= 1) {
        if (t < off) { sp[t] += sp[t + off]; sc[t] += sc[t + off]; }
        __syncthreads();
    }
    if (t == 0) out[g] = sp[0] / fmaxf(sc[0], 1.0f) + bl[0];
}

extern "C" void kernel_launch(void* const* d_in, const int* in_sizes, int n_in,
                              void* d_out, int out_size, void* d_ws, size_t ws_size,
                              hipStream_t stream) {
    const float* x  = (const float*)d_in[0];
    const float* W1 = (const float*)d_in[1];
    const float* b1 = (const float*)d_in[2];
    const float* W2 = (const float*)d_in[3];
    const float* b2 = (const float*)d_in[4];
    const float* Wl = (const float*)d_in[5];
    const float* bl = (const float*)d_in[6];
    const int* edge_index = (const int*)d_in[7];
    const int* batch      = (const int*)d_in[8];

    const int n = in_sizes[0] / 128;   // 50000 (< 65536 for ushort cols)
    const int E = in_sizes[7] / 2;     // 800000
    const int G = out_size;            // 256
    const int* src = edge_index;
    const int* dst = edge_index + E;

    char* ws = (char*)d_ws;
    size_t off = 0;
    auto alloc = [&](size_t bytes) { void* p = ws + off; off = (off + bytes + 255) & ~(size_t)255; return p; };
    int*            cntv   = (int*)           alloc((size_t)n * 4);
    float*          dinv   = (float*)         alloc((size_t)n * 4);
    int*            rowptr = (int*)           alloc((size_t)(n + 1) * 4);
    int*            excl   = (int*)           alloc((size_t)n * 4);
    int*            sums   = (int*)           alloc((size_t)256 * 4);
    unsigned short* rank   = (unsigned short*)alloc((size_t)E * 2);
    unsigned short* col    = (unsigned short*)alloc((size_t)E * 2 + 64);  // +slop
    __half*         bufA   = (__half*)        alloc((size_t)n * 64 * 2);  // h1'
    __half*         bufC   = (__half*)        alloc((size_t)n * 64 * 2);  // g1
    __half*         bufB   = (__half*)        alloc((size_t)n * 64 * 2);  // h2'
    const int PBLK = 2048;
    float*          part   = (float*)         alloc((size_t)PBLK * 256 * 4);
    float*          partc  = (float*)         alloc((size_t)PBLK * 256 * 4);

    const int T = 256;
    const int nchunks = (n + 255) / 256;
    // ---- CSR build (shared by both layers) ----
    zero32<<<(n + T - 1) / T, T, 0, stream>>>(cntv, n);
    hist_rank<<<(E + T - 1) / T, T, 0, stream>>>(dst, cntv, rank, E);
    scan1_dinv<<<nchunks, T, 0, stream>>>(cntv, excl, sums, dinv, n);
    scan2<<<1, T, 0, stream>>>(sums, nchunks);
    scan3<<<(n + 1 + T - 1) / T, T, 0, stream>>>(excl, sums, rowptr, n, E);
    fill_place<<<1024, T, 0, stream>>>(src, dst, rank, rowptr, col, E, n);

    // ---- layer 1 GEMM: h1' = fp16(dinv * (x @ W1)) ----
    gemm_bcast_scaled<128><<<768, T, 0, stream>>>(x, W1, dinv, bufA, n);
    // ---- layer 1 agg: g1 = fp16(relu(dinv * sum + b1)) ----
    agg_relu16<<<2048, T, 0, stream>>>(bufA, rowptr, col, dinv, b1, bufC, n);
    // ---- layer 2 GEMM: h2' = fp16(dinv * (g1 @ W2)) ----
    gemm_bcast_scaled<64><<<768, T, 0, stream>>>(bufC, W2, dinv, bufB, n);
    // ---- layer 2 agg + head + pooling partials ----
    agg_pool<<<PBLK, T, 0, stream>>>(bufB, rowptr, col, dinv, b2, Wl, batch, part, partc, n);
    pool_final<<<G, T, 0, stream>>>(part, partc, bl, (float*)d_out, PBLK);
}